// Round 5
// baseline (363.932 us; speedup 1.0000x reference)
//
#include <hip/hip_runtime.h>
#include <cstdint>
#include <cstddef>

#define DD 128
#define KK 32
constexpr float EPS = 1e-8f;

typedef __bf16 bf16x8 __attribute__((ext_vector_type(8)));
typedef float f32x4 __attribute__((ext_vector_type(4)));

__device__ __forceinline__ unsigned short f2bf(float x) {
    union { float f; uint32_t u; } v; v.f = x;
    uint32_t r = v.u + 0x7FFFu + ((v.u >> 16) & 1u);   // RNE
    return (unsigned short)(r >> 16);
}
__device__ __forceinline__ float bflo(uint32_t w) {
    union { uint32_t u; float f; } v; v.u = w << 16; return v.f;
}
__device__ __forceinline__ float bfhi(uint32_t w) {
    union { uint32_t u; float f; } v; v.u = w & 0xFFFF0000u; return v.f;
}

// DPP rotate-fold: x += row_ror<AMT>(x). After amounts 8,4,2,1 every lane of
// each 16-lane DPP row (== one quad group) holds the full 16-lane sum.
template <int CTRL>
__device__ __forceinline__ float dpp_fold(float x) {
    union { float f; int i; } u, r;
    u.f = x;
    r.i = __builtin_amdgcn_update_dpp(0, u.i, CTRL, 0xF, 0xF, false);
    return x + r.f;
}
__device__ __forceinline__ f32x4 quad_allsum(f32x4 v) {
    #pragma unroll
    for (int c = 0; c < 4; ++c) {
        float x = v[c];
        x = dpp_fold<0x128>(x);   // row_ror:8
        x = dpp_fold<0x124>(x);   // row_ror:4
        x = dpp_fold<0x122>(x);   // row_ror:2
        x = dpp_fold<0x121>(x);   // row_ror:1
        v[c] = x;
    }
    return v;
}

__device__ __forceinline__ float pick(const f32x4& a, const f32x4& b, int rt, int reg) {
    float v0 = rt ? b[0] : a[0];
    float v1 = rt ? b[1] : a[1];
    float v2 = rt ? b[2] : a[2];
    float v3 = rt ? b[3] : a[3];
    float lo = (reg & 1) ? v1 : v0;
    float hi = (reg & 1) ? v3 : v2;
    return (reg & 2) ? hi : lo;
}

// ---------------- prep kernel: all format conversions in ONE launch ---------
// Xf[rg][c][mm][8]: row = rg*16+mm, d = c*8+j  -> off = rg*2048 + c*128 + mm*8
// Wf[k][eg][c][mm][8]: W[k][d=c*8+j][e=eg*16+mm]
// cvt index map is mm-fast so the 16B fragment stores are fully coalesced.
__global__ __launch_bounds__(256) void prep_kernel(
    const float* __restrict__ x1, const float* __restrict__ x2,
    const float* __restrict__ W1, const float* __restrict__ W2,
    __bf16* __restrict__ X1f, __bf16* __restrict__ X2f,
    __bf16* __restrict__ W1f, __bf16* __restrict__ W2f,
    int cvt_half, int wf_half)
{
    int bb = blockIdx.x;
    if (bb < 2 * cvt_half) {
        const float* src; __bf16* dst;
        if (bb >= cvt_half) { src = x2; dst = X2f; bb -= cvt_half; }
        else                { src = x1; dst = X1f; }
        int idx = bb * 256 + threadIdx.x;
        int mm = idx & 15, c = (idx >> 4) & 15, rg = idx >> 8;
        const float* p = src + (size_t)(rg * 16 + mm) * DD + c * 8;
        float4 f0 = *reinterpret_cast<const float4*>(p);
        float4 f1 = *reinterpret_cast<const float4*>(p + 4);
        ushort4 o0, o1;
        o0.x = f2bf(f0.x); o0.y = f2bf(f0.y); o0.z = f2bf(f0.z); o0.w = f2bf(f0.w);
        o1.x = f2bf(f1.x); o1.y = f2bf(f1.y); o1.z = f2bf(f1.z); o1.w = f2bf(f1.w);
        size_t off = (size_t)rg * 2048 + (size_t)c * 128 + (size_t)mm * 8;
        *reinterpret_cast<ushort4*>(dst + off)     = o0;
        *reinterpret_cast<ushort4*>(dst + off + 4) = o1;
    } else {
        bb -= 2 * cvt_half;
        const float* W; __bf16* Wf;
        if (bb >= wf_half) { W = W2; Wf = W2f; bb -= wf_half; }
        else               { W = W1; Wf = W1f; }
        int idx = bb * 256 + threadIdx.x;
        int mm = idx & 15;
        int c  = (idx >> 4) & 15;
        int eg = (idx >> 8) & 7;
        int k  = idx >> 11;
        const float* Wk = W + (size_t)k * DD * DD;
        int e = eg * 16 + mm;
        ushort4 o0, o1;
        o0.x = f2bf(Wk[(size_t)(c * 8 + 0) * DD + e]);
        o0.y = f2bf(Wk[(size_t)(c * 8 + 1) * DD + e]);
        o0.z = f2bf(Wk[(size_t)(c * 8 + 2) * DD + e]);
        o0.w = f2bf(Wk[(size_t)(c * 8 + 3) * DD + e]);
        o1.x = f2bf(Wk[(size_t)(c * 8 + 4) * DD + e]);
        o1.y = f2bf(Wk[(size_t)(c * 8 + 5) * DD + e]);
        o1.z = f2bf(Wk[(size_t)(c * 8 + 6) * DD + e]);
        o1.w = f2bf(Wk[(size_t)(c * 8 + 7) * DD + e]);
        size_t off = ((size_t)(k * 8 + eg)) * 2048 + (size_t)c * 128 + (size_t)mm * 8;
        *reinterpret_cast<ushort4*>(Wf + off)     = o0;
        *reinterpret_cast<ushort4*>(Wf + off + 4) = o1;
    }
}

// ---------------- main fused kernel ----------------
// 1D grid 8192, XCD-aware decode: xcd=b&7, k=(b>>3)&31 fast, ntile per-XCD.
// Each wave owns 32 rows x ALL 128 cols (rt=2, et=8): the entire per-row
// e-reduction is in-wave -> NO LDS, NO __syncthreads anywhere. Reductions via
// DPP rotate-folds (VALU pipe). B fragments from global (L1 dedupes: all 4
// waves read the identical W[k] stream).
__global__ __launch_bounds__(256, 2) void ntn_main(
    const __bf16* __restrict__ X1f, const __bf16* __restrict__ X2f,
    const __bf16* __restrict__ W1f, const __bf16* __restrict__ W2f,
    const float* __restrict__ V, const float* __restrict__ bias,
    float* __restrict__ out, int nt_per_xcd)
{
    const int b     = blockIdx.x;
    const int xcd   = b & 7;
    const int j     = b >> 3;
    const int k     = j & 31;
    const int ntile = xcd * nt_per_xcd + (j >> 5);
    const int tid   = threadIdx.x;
    const int wave  = tid >> 6;
    const int lane  = tid & 63;
    const int m     = lane & 15;
    const int quad  = lane >> 4;
    const int wrow  = wave * 32;

    f32x4 acc1[2][8], acc2[2][8];
    #pragma unroll
    for (int rt = 0; rt < 2; ++rt)
        #pragma unroll
        for (int et = 0; et < 8; ++et) {
            acc1[rt][et] = f32x4{0.f, 0.f, 0.f, 0.f};
            acc2[rt][et] = f32x4{0.f, 0.f, 0.f, 0.f};
        }

    const __bf16* w1p = W1f + (size_t)k * 16384;
    const __bf16* w2p = W2f + (size_t)k * 16384;
    const int rgb = ntile * 8 + wave * 2;

    #pragma unroll
    for (int ks = 0; ks < 4; ++ks) {
        bf16x8 a1[2], a2[2];
        #pragma unroll
        for (int rt = 0; rt < 2; ++rt) {
            const size_t off = (size_t)(rgb + rt) * 2048 + ks * 512 + lane * 8;
            a1[rt] = *reinterpret_cast<const bf16x8*>(X1f + off);
            a2[rt] = *reinterpret_cast<const bf16x8*>(X2f + off);
        }
        #pragma unroll
        for (int et = 0; et < 8; ++et) {
            const size_t boff = (size_t)et * 2048 + ks * 512 + lane * 8;
            bf16x8 b1 = *reinterpret_cast<const bf16x8*>(w1p + boff);
            bf16x8 b2 = *reinterpret_cast<const bf16x8*>(w2p + boff);
            #pragma unroll
            for (int rt = 0; rt < 2; ++rt) {
                acc1[rt][et] = __builtin_amdgcn_mfma_f32_16x16x32_bf16(a1[rt], b1, acc1[rt][et], 0, 0, 0);
                acc2[rt][et] = __builtin_amdgcn_mfma_f32_16x16x32_bf16(a2[rt], b2, acc2[rt][et], 0, 0, 0);
            }
        }
    }

    // ---- in-wave epilogue: dot / |x1t|^2 / |x2t|^2 per row ----
    f32x4 pd[2], q1[2], q2[2];
    #pragma unroll
    for (int rt = 0; rt < 2; ++rt) {
        f32x4 d = {0.f, 0.f, 0.f, 0.f};
        f32x4 a = {0.f, 0.f, 0.f, 0.f};
        f32x4 c = {0.f, 0.f, 0.f, 0.f};
        #pragma unroll
        for (int et = 0; et < 8; ++et) {
            d += acc1[rt][et] * acc2[rt][et];
            a += acc1[rt][et] * acc1[rt][et];
            c += acc2[rt][et] * acc2[rt][et];
        }
        pd[rt] = quad_allsum(d);
        q1[rt] = quad_allsum(a);
        q2[rt] = quad_allsum(c);
    }

    // lane m (0..15): rowslot = m&7 -> rt=(m>>2)&1, reg=m&3; half = m>>3.
    const int rsel = m & 7;
    const int rtl  = rsel >> 2;
    const int reg  = rsel & 3;
    const int row  = wrow + rtl * 16 + quad * 4 + reg;   // row within 128-tile

    // ---- part2: 2 lanes per row compute the two 128-halves of xcat.V[k] ----
    const __bf16* Xsrc = (m < 8) ? X1f : X2f;
    const float*  Vp   = V + (size_t)k * 256 + ((m < 8) ? 0 : 128);
    const size_t  cb   = (size_t)(ntile * 8 + (row >> 4)) * 2048 + (size_t)(row & 15) * 8;
    float p2 = 0.f;
    #pragma unroll
    for (int c = 0; c < 16; ++c) {
        uint4 u = *reinterpret_cast<const uint4*>(Xsrc + cb + c * 128);
        float4 v0 = *reinterpret_cast<const float4*>(Vp + c * 8);
        float4 v1 = *reinterpret_cast<const float4*>(Vp + c * 8 + 4);
        p2 += bflo(u.x) * v0.x + bfhi(u.x) * v0.y
            + bflo(u.y) * v0.z + bfhi(u.y) * v0.w
            + bflo(u.z) * v1.x + bfhi(u.z) * v1.y
            + bflo(u.w) * v1.z + bfhi(u.w) * v1.w;
    }
    p2 = dpp_fold<0x128>(p2);   // combine lane m with partner m^8

    if (m < 8) {
        float dot = pick(pd[0], pd[1], rtl, reg);
        float s1  = pick(q1[0], q1[1], rtl, reg);
        float s2  = pick(q2[0], q2[1], rtl, reg);
        float n1 = fmaxf(sqrtf(s1), EPS);
        float n2 = fmaxf(sqrtf(s2), EPS);
        float tot = dot / (n1 * n2) + p2 + bias[k];
        out[((size_t)ntile * 128 + row) * KK + k] = fmaxf(tot, 0.f);
    }
}

extern "C" void kernel_launch(void* const* d_in, const int* in_sizes, int n_in,
                              void* d_out, int out_size, void* d_ws, size_t ws_size,
                              hipStream_t stream) {
    const float* x1 = (const float*)d_in[0];
    const float* x2 = (const float*)d_in[1];
    const float* W1 = (const float*)d_in[2];
    const float* W2 = (const float*)d_in[3];
    const float* V  = (const float*)d_in[4];
    const float* b  = (const float*)d_in[5];
    float* out = (float*)d_out;

    const int N = in_sizes[0] / DD;   // 32768

    __bf16* X1f = (__bf16*)d_ws;
    __bf16* X2f = X1f + (size_t)N * DD;
    __bf16* W1f = X2f + (size_t)N * DD;
    __bf16* W2f = W1f + (size_t)KK * DD * DD;

    const int cvt_half = N * 16 / 256;            // 2048
    const int wf_half  = KK * DD * DD / 8 / 256;  // 256
    prep_kernel<<<2 * cvt_half + 2 * wf_half, 256, 0, stream>>>(
        x1, x2, W1, W2, X1f, X2f, W1f, W2f, cvt_half, wf_half);

    const int ntiles = N / 128;
    ntn_main<<<ntiles * KK, 256, 0, stream>>>(X1f, X2f, W1f, W2f, V, b, out, ntiles / 8);
}

// Round 6
// 217.778 us; speedup vs baseline: 1.6711x; 1.6711x over previous
//
#include <hip/hip_runtime.h>
#include <cstdint>
#include <cstddef>

#define DD 128
#define KK 32
constexpr float EPS = 1e-8f;

typedef __bf16 bf16x8 __attribute__((ext_vector_type(8)));
typedef float f32x4 __attribute__((ext_vector_type(4)));

__device__ __forceinline__ unsigned short f2bf(float x) {
    union { float f; uint32_t u; } v; v.f = x;
    uint32_t r = v.u + 0x7FFFu + ((v.u >> 16) & 1u);   // RNE
    return (unsigned short)(r >> 16);
}
__device__ __forceinline__ float bflo(uint32_t w) {
    union { uint32_t u; float f; } v; v.u = w << 16; return v.f;
}
__device__ __forceinline__ float bfhi(uint32_t w) {
    union { uint32_t u; float f; } v; v.u = w & 0xFFFF0000u; return v.f;
}

// 2-step butterfly over lane-xor 1,2: every lane ends with the sum of its
// 4-lane group {m&~3 .. m|3}. Pure cross-lane, no LDS arrays.
__device__ __forceinline__ f32x4 fold4(f32x4 v) {
    #pragma unroll
    for (int off = 1; off <= 2; off <<= 1) {
        f32x4 t;
        #pragma unroll
        for (int c = 0; c < 4; ++c) t[c] = __shfl_xor(v[c], off, 64);
        v += t;
    }
    return v;
}

// ---------------- prep kernel: all format conversions in ONE launch ---------
// Xf[rg][c][mm][8]: row = rg*16+mm, d = c*8+j  -> off = rg*2048 + c*128 + mm*8
// Wf[k][eg][c][mm][8]: W[k][d=c*8+j][e=eg*16+mm]
__global__ __launch_bounds__(256) void prep_kernel(
    const float* __restrict__ x1, const float* __restrict__ x2,
    const float* __restrict__ W1, const float* __restrict__ W2,
    __bf16* __restrict__ X1f, __bf16* __restrict__ X2f,
    __bf16* __restrict__ W1f, __bf16* __restrict__ W2f,
    int cvt_half, int wf_half)
{
    int bb = blockIdx.x;
    if (bb < 2 * cvt_half) {
        const float* src; __bf16* dst;
        if (bb >= cvt_half) { src = x2; dst = X2f; bb -= cvt_half; }
        else                { src = x1; dst = X1f; }
        int idx = bb * 256 + threadIdx.x;
        int mm = idx & 15, c = (idx >> 4) & 15, rg = idx >> 8;
        const float* p = src + (size_t)(rg * 16 + mm) * DD + c * 8;
        float4 f0 = *reinterpret_cast<const float4*>(p);
        float4 f1 = *reinterpret_cast<const float4*>(p + 4);
        ushort4 o0, o1;
        o0.x = f2bf(f0.x); o0.y = f2bf(f0.y); o0.z = f2bf(f0.z); o0.w = f2bf(f0.w);
        o1.x = f2bf(f1.x); o1.y = f2bf(f1.y); o1.z = f2bf(f1.z); o1.w = f2bf(f1.w);
        size_t off = (size_t)rg * 2048 + (size_t)c * 128 + (size_t)mm * 8;
        *reinterpret_cast<ushort4*>(dst + off)     = o0;
        *reinterpret_cast<ushort4*>(dst + off + 4) = o1;
    } else {
        bb -= 2 * cvt_half;
        const float* W; __bf16* Wf;
        if (bb >= wf_half) { W = W2; Wf = W2f; bb -= wf_half; }
        else               { W = W1; Wf = W1f; }
        int idx = bb * 256 + threadIdx.x;
        int mm = idx & 15;
        int c  = (idx >> 4) & 15;
        int eg = (idx >> 8) & 7;
        int k  = idx >> 11;
        const float* Wk = W + (size_t)k * DD * DD;
        int e = eg * 16 + mm;
        ushort4 o0, o1;
        o0.x = f2bf(Wk[(size_t)(c * 8 + 0) * DD + e]);
        o0.y = f2bf(Wk[(size_t)(c * 8 + 1) * DD + e]);
        o0.z = f2bf(Wk[(size_t)(c * 8 + 2) * DD + e]);
        o0.w = f2bf(Wk[(size_t)(c * 8 + 3) * DD + e]);
        o1.x = f2bf(Wk[(size_t)(c * 8 + 4) * DD + e]);
        o1.y = f2bf(Wk[(size_t)(c * 8 + 5) * DD + e]);
        o1.z = f2bf(Wk[(size_t)(c * 8 + 6) * DD + e]);
        o1.w = f2bf(Wk[(size_t)(c * 8 + 7) * DD + e]);
        size_t off = ((size_t)(k * 8 + eg)) * 2048 + (size_t)c * 128 + (size_t)mm * 8;
        *reinterpret_cast<ushort4*>(Wf + off)     = o0;
        *reinterpret_cast<ushort4*>(Wf + off + 4) = o1;
    }
}

// ---------------- main fused kernel ----------------
// 1D grid 16384. XCD decode: xcd=b&7, k=(b>>3)&31 (fast), nt = 64-row tile.
// Block = 4 waves = (mat in {x1,x2}) x (col-half). Each wave: 64 rows x 64
// cols of ONE transform -> only 64 acc regs/wave -> 3-4 waves/SIMD occupancy.
// x2t waves publish tiles via LDS for the cross-matrix dot product.
__global__ __launch_bounds__(256, 3) void ntn_main(
    const __bf16* __restrict__ X1f, const __bf16* __restrict__ X2f,
    const __bf16* __restrict__ W1f, const __bf16* __restrict__ W2f,
    const float* __restrict__ V, const float* __restrict__ bias,
    float* __restrict__ out, int nt_per_xcd)
{
    __shared__ f32x4 sTile[2][16][64];                  // 32 KB x2t tiles [eh][rt*4+et][lane]
    __shared__ __align__(16) float sRed[3][2][4][64];   // 6 KB [qty][eh][grp][row]
    __shared__ float sP2[4][64];                        // 1 KB part2 partials

    const int b    = blockIdx.x;
    const int xcd  = b & 7;
    const int k    = (b >> 3) & 31;
    const int nt   = xcd * nt_per_xcd + (b >> 8);
    const int tid  = threadIdx.x;
    const int wave = tid >> 6;
    const int lane = tid & 63;
    const int m    = lane & 15;
    const int quad = lane >> 4;
    const int mat  = wave >> 1;     // 0: x1/W1, 1: x2/W2
    const int eh   = wave & 1;      // column half

    f32x4 acc[4][4];
    #pragma unroll
    for (int rt = 0; rt < 4; ++rt)
        #pragma unroll
        for (int et = 0; et < 4; ++et) acc[rt][et] = f32x4{0.f, 0.f, 0.f, 0.f};

    const __bf16* Xp = mat ? X2f : X1f;
    const __bf16* Wp = (mat ? W2f : W1f) + (size_t)k * 16384;
    const int rgb = nt * 4;

    #pragma unroll
    for (int ks = 0; ks < 4; ++ks) {
        bf16x8 a[4], bb[4];
        #pragma unroll
        for (int rt = 0; rt < 4; ++rt)
            a[rt] = *reinterpret_cast<const bf16x8*>(
                Xp + (size_t)(rgb + rt) * 2048 + ks * 512 + lane * 8);
        #pragma unroll
        for (int et = 0; et < 4; ++et)
            bb[et] = *reinterpret_cast<const bf16x8*>(
                Wp + (size_t)(eh * 4 + et) * 2048 + ks * 512 + lane * 8);
        #pragma unroll
        for (int et = 0; et < 4; ++et)
            #pragma unroll
            for (int rt = 0; rt < 4; ++rt)
                acc[rt][et] = __builtin_amdgcn_mfma_f32_16x16x32_bf16(a[rt], bb[et], acc[rt][et], 0, 0, 0);
    }

    // ---- x2t waves publish their tiles (lane-matched layout) ----
    if (mat) {
        #pragma unroll
        for (int rt = 0; rt < 4; ++rt)
            #pragma unroll
            for (int et = 0; et < 4; ++et)
                sTile[eh][rt * 4 + et][lane] = acc[rt][et];
    }

    // ---- part2: 4 threads per row, each a 64-length quarter of xcat.V[k] ---
    {
        const int row = tid & 63, seg = tid >> 6;
        const __bf16* Xs = (seg < 2) ? X1f : X2f;
        const int c0 = (seg & 1) * 8;
        const size_t base = (size_t)(nt * 4 + (row >> 4)) * 2048 + (size_t)(row & 15) * 8;
        const float* Vp = V + (size_t)k * 256 + seg * 64;
        float p2 = 0.f;
        #pragma unroll
        for (int c = 0; c < 8; ++c) {
            uint4 u = *reinterpret_cast<const uint4*>(Xs + base + (c0 + c) * 128);
            float4 v0 = *reinterpret_cast<const float4*>(Vp + c * 8);
            float4 v1 = *reinterpret_cast<const float4*>(Vp + c * 8 + 4);
            p2 += bflo(u.x) * v0.x + bfhi(u.x) * v0.y
                + bflo(u.y) * v0.z + bfhi(u.y) * v0.w
                + bflo(u.z) * v1.x + bfhi(u.z) * v1.y
                + bflo(u.w) * v1.z + bfhi(u.w) * v1.w;
        }
        sP2[seg][row] = p2;
    }

    __syncthreads();   // tiles + part2 partials visible

    const int grp = m >> 2;
    if (mat == 0) {
        #pragma unroll
        for (int rt = 0; rt < 4; ++rt) {
            f32x4 pd = {0.f, 0.f, 0.f, 0.f};
            f32x4 q1 = {0.f, 0.f, 0.f, 0.f};
            #pragma unroll
            for (int et = 0; et < 4; ++et) {
                f32x4 a1v = acc[rt][et];
                f32x4 o   = sTile[eh][rt * 4 + et][lane];
                pd += a1v * o;
                q1 += a1v * a1v;
            }
            pd = fold4(pd);
            q1 = fold4(q1);
            if ((m & 3) == 0) {
                const int rb = rt * 16 + quad * 4;
                *reinterpret_cast<f32x4*>(&sRed[0][eh][grp][rb]) = pd;
                *reinterpret_cast<f32x4*>(&sRed[1][eh][grp][rb]) = q1;
            }
        }
    } else {
        #pragma unroll
        for (int rt = 0; rt < 4; ++rt) {
            f32x4 q2 = {0.f, 0.f, 0.f, 0.f};
            #pragma unroll
            for (int et = 0; et < 4; ++et) q2 += acc[rt][et] * acc[rt][et];
            q2 = fold4(q2);
            if ((m & 3) == 0) {
                const int rb = rt * 16 + quad * 4;
                *reinterpret_cast<f32x4*>(&sRed[2][eh][grp][rb]) = q2;
            }
        }
    }

    __syncthreads();

    if (tid < 64) {
        const int row = tid;
        float dot = 0.f, s1 = 0.f, s2 = 0.f;
        #pragma unroll
        for (int e2 = 0; e2 < 2; ++e2)
            #pragma unroll
            for (int g = 0; g < 4; ++g) {
                dot += sRed[0][e2][g][row];
                s1  += sRed[1][e2][g][row];
                s2  += sRed[2][e2][g][row];
            }
        float p2 = sP2[0][row] + sP2[1][row] + sP2[2][row] + sP2[3][row];
        float n1 = fmaxf(sqrtf(s1), EPS);
        float n2 = fmaxf(sqrtf(s2), EPS);
        float tot = dot / (n1 * n2) + p2 + bias[k];
        out[((size_t)nt * 64 + row) * KK + k] = fmaxf(tot, 0.f);
    }
}

extern "C" void kernel_launch(void* const* d_in, const int* in_sizes, int n_in,
                              void* d_out, int out_size, void* d_ws, size_t ws_size,
                              hipStream_t stream) {
    const float* x1 = (const float*)d_in[0];
    const float* x2 = (const float*)d_in[1];
    const float* W1 = (const float*)d_in[2];
    const float* W2 = (const float*)d_in[3];
    const float* V  = (const float*)d_in[4];
    const float* b  = (const float*)d_in[5];
    float* out = (float*)d_out;

    const int N = in_sizes[0] / DD;   // 32768

    __bf16* X1f = (__bf16*)d_ws;
    __bf16* X2f = X1f + (size_t)N * DD;
    __bf16* W1f = X2f + (size_t)N * DD;
    __bf16* W2f = W1f + (size_t)KK * DD * DD;

    const int cvt_half = N * 16 / 256;            // 2048
    const int wf_half  = KK * DD * DD / 8 / 256;  // 256
    prep_kernel<<<2 * cvt_half + 2 * wf_half, 256, 0, stream>>>(
        x1, x2, W1, W2, X1f, X2f, W1f, W2f, cvt_half, wf_half);

    const int ntiles64 = N / 64;                  // 512
    ntn_main<<<ntiles64 * KK, 256, 0, stream>>>(X1f, X2f, W1f, W2f, V, b, out,
                                                ntiles64 / 8);
}